// Round 7
// baseline (17514.502 us; speedup 1.0000x reference)
//
#include <hip/hip_runtime.h>
#include <hip/hip_bf16.h>

// Problem constants (N=64, D=64, H=64, W=64, K=512)
#define VQ_D   64
#define VQ_K   512
#define VQ_HW  4096
#define VQ_M   262144
#define VQ_LOSS_OFF 16777216
#define VQ_IDX_OFF  16777217
#define VQ_EPS  3.0e-4f
#define VQ_BIAS 0.25f

typedef __bf16 bf16x8v __attribute__((ext_vector_type(8)));
typedef float  f32x16  __attribute__((ext_vector_type(16)));

union BF8 { unsigned short u[8]; uint4 q4; bf16x8v v; };

__device__ __forceinline__ unsigned short f2bf(float f) {
    unsigned u = __builtin_bit_cast(unsigned, f);
    u += 0x7FFFu + ((u >> 16) & 1u);
    return (unsigned short)(u >> 16);
}
__device__ __forceinline__ float bf2f(unsigned short b) {
    return __builtin_bit_cast(float, ((unsigned)b) << 16);
}
__device__ __forceinline__ unsigned umn(unsigned a, unsigned b) { return a < b ? a : b; }
__device__ __forceinline__ unsigned umx(unsigned a, unsigned b) { return a > b ? a : b; }

// ---------------------------------------------------------------------------
// Prep: esq[k] (numpy pairwise, bitwise) + single-bf16 A-frags (R5-validated).
// kfrag: [tile t(16)][frag f(5)][lane(64)] uint4.
//   f<4 : bf16(-2*e[f*16+k]);  f=4: bias row hi/lo of (0.25+esq), B=(1,1,0..)
// A-frag (32x32x16): lane l holds A[m=l&31][k=(l>>5)*8+j].
// => acc = 0.25 + esq - 2*dot (positive => uint-bit-comparable).
// ---------------------------------------------------------------------------
__global__ void vq_prep(const float* __restrict__ emb, float* __restrict__ esq,
                        uint4* __restrict__ kfrag,
                        double* __restrict__ loss_acc, int* __restrict__ cnt) {
#pragma clang fp contract(off)
    int k = blockIdx.x * 256 + threadIdx.x;
    if (k == 0) { *loss_acc = 0.0; *cnt = 0; }
    if (k < VQ_K) {
        const float* e = emb + k * VQ_D;
        float p[VQ_D];
#pragma unroll
        for (int d = 0; d < VQ_D; ++d) p[d] = e[d] * e[d];
        float r[8];
#pragma unroll
        for (int j = 0; j < 8; ++j) r[j] = p[j];
#pragma unroll
        for (int i = 8; i < VQ_D; i += 8)
#pragma unroll
            for (int j = 0; j < 8; ++j) r[j] += p[i + j];
        float es = ((r[0] + r[1]) + (r[2] + r[3])) + ((r[4] + r[5]) + (r[6] + r[7]));
        esq[k] = es;

        float sc = VQ_BIAS + es;
        unsigned short bhi = f2bf(sc);
        unsigned short blo = f2bf(sc - bf2f(bhi));

        int t = k >> 5, c = k & 31;
#pragma unroll
        for (int q = 0; q < 4; ++q)
#pragma unroll
            for (int h = 0; h < 2; ++h) {
                BF8 tmp;
#pragma unroll
                for (int j = 0; j < 8; ++j)
                    tmp.u[j] = f2bf(-2.0f * e[q * 16 + h * 8 + j]);
                kfrag[(t * 5 + q) * 64 + h * 32 + c] = tmp.q4;
            }
        BF8 tb;
#pragma unroll
        for (int j = 0; j < 8; ++j) tb.u[j] = 0;
        tb.u[0] = bhi; tb.u[1] = blo;
        kfrag[(t * 5 + 4) * 64 + c] = tb.q4;           // half 0 (k=0,1 live)
        BF8 tz;
#pragma unroll
        for (int j = 0; j < 8; ++j) tz.u[j] = 0;
        kfrag[(t * 5 + 4) * 64 + 32 + c] = tz.q4;      // half 1 zeros
    }
}

// ---------------------------------------------------------------------------
// Screen: per point, TOP-3 candidate codes + flag. 512 thr = 8 waves = 256 pts.
// Per-lane top-3 packed keys over its 256 codes; pair-merge (lane^32) via
// min/max network; cand word = c1|c2<<9|c3<<18|flag<<27; flagged -> fb_list.
// ---------------------------------------------------------------------------
__global__ __launch_bounds__(512) void vq_screen(
        const float* __restrict__ z_e,
        const uint4* __restrict__ kfrag,
        unsigned* __restrict__ cand,
        int* __restrict__ cnt,
        int* __restrict__ fb_list)
{
    __shared__ uint4 smem[2560];                      // 40 KB: 8 tiles x 5 frags
    const int tid = threadIdx.x;
    const int w   = tid >> 6;
    const int l   = tid & 63;
    const int c   = l & 31;
    const int h   = l >> 5;

    const int m0 = (blockIdx.x * 8 + w) * 32;
    const int n  = m0 >> 12;
    const int hw = (m0 & 4095) + c;
    const float* zb = z_e + (size_t)n * (VQ_D * VQ_HW) + hw;

    // z bf16 B-frags: B[k=(l>>5)*8+j][col=l&31], d = q*16 + h*8 + j
    bf16x8v bz[4];
#pragma unroll
    for (int q = 0; q < 4; ++q) {
        BF8 t;
#pragma unroll
        for (int j = 0; j < 8; ++j)
            t.u[j] = f2bf(zb[(q * 16 + h * 8 + j) * VQ_HW]);
        bz[q] = t.v;
    }
    BF8 tob;
#pragma unroll
    for (int j = 0; j < 8; ++j) tob.u[j] = 0;
    if (h == 0) { tob.u[0] = 0x3F80; tob.u[1] = 0x3F80; }
    const bf16x8v bones = tob.v;

    int coder[16];
#pragma unroll
    for (int r = 0; r < 16; ++r) coder[r] = (r & 3) + 8 * (r >> 2) + 4 * h;

    unsigned m1 = 0xFFFFFFFFu, m2 = 0xFFFFFFFFu, m3 = 0xFFFFFFFFu;
    const unsigned SMASK = 0xFFFFFE00u;

    for (int ht = 0; ht < 2; ++ht) {                  // two 8-tile halves
        __syncthreads();
#pragma unroll
        for (int i = 0; i < 5; ++i)
            smem[i * 512 + tid] = kfrag[ht * 2560 + i * 512 + tid];
        __syncthreads();

        for (int t8 = 0; t8 < 8; ++t8) {
            const int base = t8 * 5 * 64;
            f32x16 acc;
#pragma unroll
            for (int r = 0; r < 16; ++r) acc[r] = 0.f;
#pragma unroll
            for (int q = 0; q < 4; ++q) {
                bf16x8v a = __builtin_bit_cast(bf16x8v, smem[base + q * 64 + l]);
                acc = __builtin_amdgcn_mfma_f32_32x32x16_bf16(a, bz[q], acc, 0, 0, 0);
            }
            bf16x8v ab = __builtin_bit_cast(bf16x8v, smem[base + 4 * 64 + l]);
            acc = __builtin_amdgcn_mfma_f32_32x32x16_bf16(ab, bones, acc, 0, 0, 0);

#pragma unroll
            for (int r = 0; r < 16; ++r) {
                unsigned key = (__builtin_bit_cast(unsigned, acc[r]) & SMASK)
                               | (unsigned)coder[r];
                m3 = umn(m3, umx(m2, key));
                m2 = umn(m2, umx(m1, key));
                m1 = umn(m1, key);
                coder[r] += 32;
            }
        }
    }

    // merge sorted triples of the lane pair (codes of the two halves disjoint)
    unsigned b1 = (unsigned)__shfl_xor((int)m1, 32, 64);
    unsigned b2 = (unsigned)__shfl_xor((int)m2, 32, 64);
    unsigned b3 = (unsigned)__shfl_xor((int)m3, 32, 64);
    unsigned n1 = umn(m1, b1);
    unsigned n2 = umn(umx(m1, b1), umn(m2, b2));
    unsigned n3 = umn(umn(m3, b3), umn(umx(m1, b2), umx(m2, b1)));

    const float s1 = __builtin_bit_cast(float, n1 & SMASK);
    const float s3 = __builtin_bit_cast(float, n3 & SMASK);
    const bool flagged = (s3 - s1) <= VQ_EPS;

    if (h == 0)
        cand[m0 + c] = (n1 & 511u) | ((n2 & 511u) << 9) | ((n3 & 511u) << 18)
                       | (flagged ? (1u << 27) : 0u);

    // compact flagged to fb_list (lanes 0..31 represent the 32 points)
    unsigned long long bal = __ballot(flagged);
    unsigned mask32 = (unsigned)(bal & 0xFFFFFFFFull);
    int cw = __popc(mask32);
    int basepos = 0;
    if (l == 0 && cw) basepos = atomicAdd(cnt, cw);
    basepos = __shfl(basepos, 0, 64);
    if (h == 0 && flagged)
        fb_list[basepos + __popc(mask32 & ((1u << c) - 1u))] = m0 + c;
}

// ---------------------------------------------------------------------------
// Candidate kernel: thread-per-point, EXACT bitwise-numpy distance on the 3
// candidates; lexicographic (dist,code) = np.argmin semantics. Writes idx,
// z_q, loss (loss skipped for flagged; fallback owns those fully).
// ---------------------------------------------------------------------------
__global__ __launch_bounds__(256) void vq_cand(
        const float* __restrict__ z_e,
        const float* __restrict__ emb,
        const float* __restrict__ esq,
        const unsigned* __restrict__ cand,
        float* __restrict__ out,
        float* __restrict__ out_idx,
        double* __restrict__ loss_acc)
{
#pragma clang fp contract(off)
    const int m  = blockIdx.x * 256 + threadIdx.x;
    const int n  = m >> 12;
    const int hw = m & 4095;

    const unsigned cw = cand[m];
    const bool flagged = (cw >> 27) & 1u;
    int codes[3] = { (int)(cw & 511u), (int)((cw >> 9) & 511u),
                     (int)((cw >> 18) & 511u) };

    const float* zp = z_e + (size_t)n * (VQ_D * VQ_HW) + hw;
    float z[VQ_D];
#pragma unroll
    for (int d = 0; d < VQ_D; ++d) z[d] = zp[d * VQ_HW];   // coalesced per d

    // z_sq: numpy pairwise (products rounded, 8 accs stride-8, tree combine)
    float p[VQ_D];
#pragma unroll
    for (int d = 0; d < VQ_D; ++d) p[d] = z[d] * z[d];
    float r[8];
#pragma unroll
    for (int j = 0; j < 8; ++j) r[j] = p[j];
#pragma unroll
    for (int i = 8; i < VQ_D; i += 8)
#pragma unroll
        for (int j = 0; j < 8; ++j) r[j] += p[i + j];
    const float zsq = ((r[0] + r[1]) + (r[2] + r[3])) + ((r[4] + r[5]) + (r[6] + r[7]));

    unsigned long long best = ~0ull;
#pragma unroll
    for (int j = 0; j < 3; ++j) {
        const int code = codes[j];
        const float4* er = (const float4*)(emb + code * VQ_D);
        float a = 0.f;
#pragma unroll
        for (int q = 0; q < 16; ++q) {                 // sequential fma chain
            float4 ev = er[q];
            a = __builtin_fmaf(z[q * 4 + 0], ev.x, a);
            a = __builtin_fmaf(z[q * 4 + 1], ev.y, a);
            a = __builtin_fmaf(z[q * 4 + 2], ev.z, a);
            a = __builtin_fmaf(z[q * 4 + 3], ev.w, a);
        }
        float dist = (zsq + esq[code]) - 2.0f * a;
        unsigned long long key =
            (((unsigned long long)__builtin_bit_cast(unsigned, dist)) << 10)
            | (unsigned)code;
        best = key < best ? key : best;
    }
    const int win = (int)(best & 1023ull);

    out_idx[m] = (float)win;
    const float* eb = emb + win * VQ_D;
    float* op = out + (size_t)n * (VQ_D * VQ_HW) + hw;
    float lsum = 0.f;
#pragma unroll
    for (int d = 0; d < VQ_D; ++d) {
        float q = eb[d];
        op[d * VQ_HW] = q;                             // coalesced per d
        float df = z[d] - q;
        lsum = __builtin_fmaf(df, df, lsum);
    }
    if (flagged) lsum = 0.f;                           // fallback adds theirs

    for (int off = 32; off > 0; off >>= 1)
        lsum += __shfl_down(lsum, off, 64);
    if ((threadIdx.x & 63) == 0) atomicAdd(loss_acc, (double)lsum);
}

// ---------------------------------------------------------------------------
// Fallback: block per flagged point; 4 stages of 128 codebook rows staged in
// XOR-swizzled LDS (bank-conflict-free divergent reads); exact bitwise-numpy
// distance, u64 (dist<<10|code) min = first-occurrence argmin.
// ---------------------------------------------------------------------------
__global__ __launch_bounds__(256) void vq_fallback(
        const float* __restrict__ z_e,
        const float* __restrict__ emb,
        const float* __restrict__ esq,
        float* __restrict__ out,
        float* __restrict__ out_idx,
        const int* __restrict__ cnt,
        const int* __restrict__ fb_list,
        double* __restrict__ loss_acc)
{
#pragma clang fp contract(off)
    __shared__ float lut[128 * 64];                    // 32 KB, swizzled
    __shared__ float zs[VQ_D];
    __shared__ unsigned long long wmin[4];
    __shared__ int winner;
    const int tid = threadIdx.x;
    const int total = *cnt;

    for (int it = blockIdx.x; it < total; it += gridDim.x) {
        __syncthreads();
        const int m  = fb_list[it];
        const int n  = m >> 12;
        const int hw = m & 4095;
        if (tid < VQ_D)
            zs[tid] = z_e[(size_t)n * (VQ_D * VQ_HW) + tid * VQ_HW + hw];
        __syncthreads();

        float r[8];
#pragma unroll
        for (int j = 0; j < 8; ++j) r[j] = zs[j] * zs[j];
#pragma unroll
        for (int i = 8; i < VQ_D; i += 8)
#pragma unroll
            for (int j = 0; j < 8; ++j) {
                float t = zs[i + j] * zs[i + j];
                r[j] += t;
            }
        const float zsq = ((r[0] + r[1]) + (r[2] + r[3])) + ((r[4] + r[5]) + (r[6] + r[7]));

        unsigned long long best = ~0ull;
        for (int s = 0; s < 4; ++s) {
            __syncthreads();
#pragma unroll
            for (int j = 0; j < 32; ++j) {             // stage 128 rows, swizzled
                int idx = j * 256 + tid;
                int row = idx >> 6, d = idx & 63;
                lut[row * 64 + ((d + row) & 63)] = emb[s * 8192 + idx];
            }
            __syncthreads();
            if (tid < 128) {
                const int code = s * 128 + tid;
                float a = 0.f;
#pragma unroll
                for (int d = 0; d < VQ_D; ++d)
                    a = __builtin_fmaf(zs[d], lut[tid * 64 + ((d + tid) & 63)], a);
                float dist = (zsq + esq[code]) - 2.0f * a;
                unsigned long long key =
                    (((unsigned long long)__builtin_bit_cast(unsigned, dist)) << 10)
                    | (unsigned)code;
                best = key < best ? key : best;
            }
        }
#pragma unroll
        for (int off = 32; off > 0; off >>= 1) {
            unsigned long long o = __shfl_down(best, off, 64);
            best = o < best ? o : best;
        }
        if ((tid & 63) == 0) wmin[tid >> 6] = best;
        __syncthreads();
        if (tid == 0) {
            unsigned long long b = wmin[0];
            b = wmin[1] < b ? wmin[1] : b;
            b = wmin[2] < b ? wmin[2] : b;
            b = wmin[3] < b ? wmin[3] : b;
            winner = (int)(b & 1023ull);
            out_idx[m] = (float)winner;
        }
        __syncthreads();

        float lsum = 0.f;
        if (tid < VQ_D) {
            float q = emb[(winner << 6) + tid];
            out[(size_t)n * (VQ_D * VQ_HW) + tid * VQ_HW + hw] = q;
            float df = zs[tid] - q;
            lsum = df * df;
        }
        if (tid < 64) {
#pragma unroll
            for (int off = 32; off > 0; off >>= 1)
                lsum += __shfl_down(lsum, off, 64);
            if (tid == 0) atomicAdd(loss_acc, (double)lsum);
        }
    }
}

__global__ void vq_fin(const double* __restrict__ loss_acc, float* __restrict__ out) {
    if (threadIdx.x == 0)
        out[VQ_LOSS_OFF] = (float)(*loss_acc / 16777216.0);
}

extern "C" void kernel_launch(void* const* d_in, const int* in_sizes, int n_in,
                              void* d_out, int out_size, void* d_ws, size_t ws_size,
                              hipStream_t stream) {
    const float* z_e = (const float*)d_in[0];
    const float* emb = (const float*)d_in[1];
    float* out = (float*)d_out;
    float* out_idx = out + VQ_IDX_OFF;

    // ws layout:
    //   0      : double loss_acc                 (8 B)
    //   8      : int cnt                         (4 B + pad)
    //   16     : float esq[512]                  (2048 B)  -> 2064
    //   2064   : uint4 kfrag[5120]               (81920 B) -> 83984
    //   83984  : unsigned cand[262144]           (1 MB)    -> 1132560
    //   1132560: int fb_list[262144]             (1 MB)
    char* ws = (char*)d_ws;
    double*   loss_acc = (double*)ws;
    int*      cnt      = (int*)(ws + 8);
    float*    esq      = (float*)(ws + 16);
    uint4*    kfrag    = (uint4*)(ws + 2064);
    unsigned* cand     = (unsigned*)(ws + 83984);
    int*      fb_list  = (int*)(ws + 1132560);

    vq_prep<<<2, 256, 0, stream>>>(emb, esq, kfrag, loss_acc, cnt);
    vq_screen<<<VQ_M / 256, 512, 0, stream>>>(z_e, kfrag, cand, cnt, fb_list);
    vq_cand<<<VQ_M / 256, 256, 0, stream>>>(z_e, emb, esq, cand, out, out_idx, loss_acc);
    vq_fallback<<<2048, 256, 0, stream>>>(z_e, emb, esq, out, out_idx, cnt, fb_list, loss_acc);
    vq_fin<<<1, 64, 0, stream>>>(loss_acc, out);
}